// Round 2
// baseline (323.520 us; speedup 1.0000x reference)
//
#include <hip/hip_runtime.h>

#define N_TOK 131072
#define K_CODES 512
#define DIM 64

// numpy pairwise_sum replication for n=64 over terms fl(v[d]*v[d]):
//   r[0..7] = t[0..7]; for i=8..56 step 8: r[j] += t[i+j];
//   res = ((r0+r1)+(r2+r3)) + ((r4+r5)+(r6+r7))
// All ops strict IEEE fp32 (no contraction): __fmul_rn / __fadd_rn.
__device__ __forceinline__ float np_sumsq64(const float* v) {
    float r[8];
#pragma unroll
    for (int j = 0; j < 8; ++j) r[j] = __fmul_rn(v[j], v[j]);
#pragma unroll
    for (int i = 8; i < 64; i += 8) {
#pragma unroll
        for (int j = 0; j < 8; ++j)
            r[j] = __fadd_rn(r[j], __fmul_rn(v[i + j], v[i + j]));
    }
    return __fadd_rn(__fadd_rn(__fadd_rn(r[0], r[1]), __fadd_rn(r[2], r[3])),
                     __fadd_rn(__fadd_rn(r[4], r[5]), __fadd_rn(r[6], r[7])));
}

__global__ __launch_bounds__(256) void vq_prep(const float* __restrict__ cb,
                                               float* __restrict__ c2) {
    int k = blockIdx.x * 256 + threadIdx.x;
    if (k < K_CODES) {
        float v[DIM];
#pragma unroll
        for (int d = 0; d < DIM; ++d) v[d] = cb[k * DIM + d];
        c2[k] = np_sumsq64(v);
    }
}

__global__ __launch_bounds__(256) void vq_main(
    const float* __restrict__ x, const float* __restrict__ cb,
    const float* __restrict__ c2, float* __restrict__ out,
    double* __restrict__ loss_acc)
{
    const int t = blockIdx.x * 256 + threadIdx.x;

    float xr[DIM];
    {
        const float4* xv = (const float4*)(x + (size_t)t * DIM);
#pragma unroll
        for (int i = 0; i < 16; ++i) {
            float4 v = xv[i];
            xr[4 * i + 0] = v.x; xr[4 * i + 1] = v.y;
            xr[4 * i + 2] = v.z; xr[4 * i + 3] = v.w;
        }
    }

    // x2 exactly as numpy computes sum(x*x, axis=-1)
    const float x2 = np_sumsq64(xr);

    // screen all K codes with BLAS-identical fp32 arithmetic:
    //   dot_k = fma-chain d ascending; d2 = (x2 - 2*dot) + c2[k]
    float best = __int_as_float(0x7f800000);  // +inf
    int bidx = 0;
#pragma unroll 2
    for (int k = 0; k < K_CODES; ++k) {
        const int kk = __builtin_amdgcn_readfirstlane(k);   // force SGPR/s_load path
        const float* c = cb + (kk << 6);
        float acc = 0.0f;
#pragma unroll
        for (int d = 0; d < DIM; ++d)
            acc = __fmaf_rn(xr[d], c[d], acc);
        float d2 = __fadd_rn(__fsub_rn(x2, __fmul_rn(2.0f, acc)), c2[kk]);
        bool p = d2 < best;       // strict < : first occurrence wins (np.argmin)
        best = p ? d2 : best;
        bidx = p ? kk : bidx;
    }

    // gather chosen code; STE output o = fl(x + fl(q - x)); loss in fp64
    double ls = 0.0;
    {
        const float* q = cb + ((size_t)bidx << 6);
        float4* o = (float4*)(out + (size_t)t * DIM);
#pragma unroll
        for (int i = 0; i < 16; ++i) {
            float4 qq = *(const float4*)(q + 4 * i);
            float e0 = __fsub_rn(qq.x, xr[4 * i + 0]);
            float e1 = __fsub_rn(qq.y, xr[4 * i + 1]);
            float e2 = __fsub_rn(qq.z, xr[4 * i + 2]);
            float e3 = __fsub_rn(qq.w, xr[4 * i + 3]);
            float4 ov;
            ov.x = __fadd_rn(xr[4 * i + 0], e0);
            ov.y = __fadd_rn(xr[4 * i + 1], e1);
            ov.z = __fadd_rn(xr[4 * i + 2], e2);
            ov.w = __fadd_rn(xr[4 * i + 3], e3);
            o[i] = ov;
            ls += (double)e0 * e0 + (double)e1 * e1
                + (double)e2 * e2 + (double)e3 * e3;
        }
    }

    // block reduce -> one double atomic per block
    for (int off = 32; off > 0; off >>= 1) ls += __shfl_down(ls, off, 64);
    __shared__ double wsum[4];
    const int lane = threadIdx.x & 63, wid = threadIdx.x >> 6;
    if (lane == 0) wsum[wid] = ls;
    __syncthreads();
    if (threadIdx.x == 0)
        atomicAdd(loss_acc, (wsum[0] + wsum[1]) + (wsum[2] + wsum[3]));
}

__global__ void vq_final(const double* __restrict__ loss_acc,
                         float* __restrict__ out_loss)
{
    if (threadIdx.x == 0 && blockIdx.x == 0) {
        double mean = *loss_acc / (double)((size_t)N_TOK * DIM);
        *out_loss = (float)(1.25 * mean);   // beta*commit + codebook, forward-equal
    }
}

extern "C" void kernel_launch(void* const* d_in, const int* in_sizes, int n_in,
                              void* d_out, int out_size, void* d_ws, size_t ws_size,
                              hipStream_t stream) {
    const float* x  = (const float*)d_in[0];
    const float* cb = (const float*)d_in[1];
    float* out = (float*)d_out;
    float* out_loss = out + (size_t)N_TOK * DIM;

    char* ws = (char*)d_ws;
    double* loss_acc = (double*)ws;          // [0,8)
    float* c2 = (float*)(ws + 64);           // 512 floats

    hipMemsetAsync(d_ws, 0, 16, stream);
    vq_prep<<<2, 256, 0, stream>>>(cb, c2);
    vq_main<<<N_TOK / 256, 256, 0, stream>>>(x, cb, c2, out, loss_acc);
    vq_final<<<1, 64, 0, stream>>>(loss_acc, out_loss);
}

// Round 3
// 291.556 us; speedup vs baseline: 1.1096x; 1.1096x over previous
//
#include <hip/hip_runtime.h>

#define N_TOK 131072
#define K_CODES 512
#define DIM 64

// numpy pairwise_sum replication for n=64 over terms fl(v[d]*v[d]):
//   r[0..7] = t[0..7]; for i=8..56 step 8: r[j] += t[i+j];
//   res = ((r0+r1)+(r2+r3)) + ((r4+r5)+(r6+r7))
// All ops strict IEEE fp32 (no contraction): __fmul_rn / __fadd_rn.
__device__ __forceinline__ float np_sumsq64(const float* v) {
    float r[8];
#pragma unroll
    for (int j = 0; j < 8; ++j) r[j] = __fmul_rn(v[j], v[j]);
#pragma unroll
    for (int i = 8; i < 64; i += 8) {
#pragma unroll
        for (int j = 0; j < 8; ++j)
            r[j] = __fadd_rn(r[j], __fmul_rn(v[i + j], v[i + j]));
    }
    return __fadd_rn(__fadd_rn(__fadd_rn(r[0], r[1]), __fadd_rn(r[2], r[3])),
                     __fadd_rn(__fadd_rn(r[4], r[5]), __fadd_rn(r[6], r[7])));
}

__global__ __launch_bounds__(256) void vq_prep(const float* __restrict__ cb,
                                               float* __restrict__ c2) {
    int k = blockIdx.x * 256 + threadIdx.x;
    if (k < K_CODES) {
        float v[DIM];
#pragma unroll
        for (int d = 0; d < DIM; ++d) v[d] = cb[k * DIM + d];
        c2[k] = np_sumsq64(v);
    }
}

// launch_bounds(256, 2): cap occupancy target at 2 waves/EU (grid only provides
// 2/SIMD anyway) -> VGPR budget 256, so xr[64] stays register-resident.
// R2's bare launch_bounds(256) made the compiler target 8 waves/EU (56 VGPR)
// and spill xr to scratch: WRITE_SIZE 97MB, 323us.
__global__ __launch_bounds__(256, 2) void vq_main(
    const float* __restrict__ x, const float* __restrict__ cb,
    const float* __restrict__ c2, float* __restrict__ out,
    double* __restrict__ loss_acc)
{
    const int t = blockIdx.x * 256 + threadIdx.x;

    float xr[DIM];
    {
        const float4* xv = (const float4*)(x + (size_t)t * DIM);
#pragma unroll
        for (int i = 0; i < 16; ++i) {
            float4 v = xv[i];
            xr[4 * i + 0] = v.x; xr[4 * i + 1] = v.y;
            xr[4 * i + 2] = v.z; xr[4 * i + 3] = v.w;
        }
    }

    // x2 exactly as numpy computes sum(x*x, axis=-1)
    const float x2 = np_sumsq64(xr);

    // Screen all K codes, 4 at a time (ILP=4 independent FMA chains).
    // Each (t,k) dot is a single fp32 FMA chain, d ascending == BLAS sgemm
    // microkernel order. d2 = (x2 - 2*dot) + c2[k], argmin strict < with k
    // ascending == np.argmin first-occurrence.
    float best = __int_as_float(0x7f800000);  // +inf
    int bidx = 0;
    for (int kg = 0; kg < K_CODES; kg += 4) {
        const int kk = __builtin_amdgcn_readfirstlane(kg);  // force SGPR/s_load
        const float* c = cb + ((size_t)kk << 6);
        float a0 = 0.f, a1 = 0.f, a2 = 0.f, a3 = 0.f;
#pragma unroll
        for (int d = 0; d < DIM; ++d) {
            a0 = __fmaf_rn(xr[d], c[d], a0);
            a1 = __fmaf_rn(xr[d], c[d + 64], a1);
            a2 = __fmaf_rn(xr[d], c[d + 128], a2);
            a3 = __fmaf_rn(xr[d], c[d + 192], a3);
        }
        float d2_0 = __fadd_rn(__fsub_rn(x2, __fmul_rn(2.0f, a0)), c2[kk + 0]);
        float d2_1 = __fadd_rn(__fsub_rn(x2, __fmul_rn(2.0f, a1)), c2[kk + 1]);
        float d2_2 = __fadd_rn(__fsub_rn(x2, __fmul_rn(2.0f, a2)), c2[kk + 2]);
        float d2_3 = __fadd_rn(__fsub_rn(x2, __fmul_rn(2.0f, a3)), c2[kk + 3]);
        bool p;
        p = d2_0 < best; best = p ? d2_0 : best; bidx = p ? kk + 0 : bidx;
        p = d2_1 < best; best = p ? d2_1 : best; bidx = p ? kk + 1 : bidx;
        p = d2_2 < best; best = p ? d2_2 : best; bidx = p ? kk + 2 : bidx;
        p = d2_3 < best; best = p ? d2_3 : best; bidx = p ? kk + 3 : bidx;
    }

    // gather chosen code; STE output o = fl(x + fl(q - x)); loss in fp64
    double ls = 0.0;
    {
        const float* q = cb + ((size_t)bidx << 6);
        float4* o = (float4*)(out + (size_t)t * DIM);
#pragma unroll
        for (int i = 0; i < 16; ++i) {
            float4 qq = *(const float4*)(q + 4 * i);
            float e0 = __fsub_rn(qq.x, xr[4 * i + 0]);
            float e1 = __fsub_rn(qq.y, xr[4 * i + 1]);
            float e2 = __fsub_rn(qq.z, xr[4 * i + 2]);
            float e3 = __fsub_rn(qq.w, xr[4 * i + 3]);
            float4 ov;
            ov.x = __fadd_rn(xr[4 * i + 0], e0);
            ov.y = __fadd_rn(xr[4 * i + 1], e1);
            ov.z = __fadd_rn(xr[4 * i + 2], e2);
            ov.w = __fadd_rn(xr[4 * i + 3], e3);
            o[i] = ov;
            ls += (double)e0 * e0 + (double)e1 * e1
                + (double)e2 * e2 + (double)e3 * e3;
        }
    }

    // block reduce -> one double atomic per block
    for (int off = 32; off > 0; off >>= 1) ls += __shfl_down(ls, off, 64);
    __shared__ double wsum[4];
    const int lane = threadIdx.x & 63, wid = threadIdx.x >> 6;
    if (lane == 0) wsum[wid] = ls;
    __syncthreads();
    if (threadIdx.x == 0)
        atomicAdd(loss_acc, (wsum[0] + wsum[1]) + (wsum[2] + wsum[3]));
}

__global__ void vq_final(const double* __restrict__ loss_acc,
                         float* __restrict__ out_loss)
{
    if (threadIdx.x == 0 && blockIdx.x == 0) {
        double mean = *loss_acc / (double)((size_t)N_TOK * DIM);
        *out_loss = (float)(1.25 * mean);   // beta*commit + codebook, forward-equal
    }
}

extern "C" void kernel_launch(void* const* d_in, const int* in_sizes, int n_in,
                              void* d_out, int out_size, void* d_ws, size_t ws_size,
                              hipStream_t stream) {
    const float* x  = (const float*)d_in[0];
    const float* cb = (const float*)d_in[1];
    float* out = (float*)d_out;
    float* out_loss = out + (size_t)N_TOK * DIM;

    char* ws = (char*)d_ws;
    double* loss_acc = (double*)ws;          // [0,8)
    float* c2 = (float*)(ws + 64);           // 512 floats

    hipMemsetAsync(d_ws, 0, 16, stream);
    vq_prep<<<2, 256, 0, stream>>>(cb, c2);
    vq_main<<<N_TOK / 256, 256, 0, stream>>>(x, cb, c2, out, loss_acc);
    vq_final<<<1, 64, 0, stream>>>(loss_acc, out_loss);
}